// Round 13
// baseline (127.390 us; speedup 1.0000x reference)
//
#include <hip/hip_runtime.h>
#include <hip/hip_bf16.h>
#include <math.h>

#define BB 8
#define TT 2048
#define EE 1024
#define HH 64
// 1/sqrt(64) * log2(e): fold into q so scores are in exp2 domain
#define QSCALE 0.18033688011112042f
#define REPS 2   // measurement round: internal x2 to surface kernels in top-5

typedef __attribute__((ext_vector_type(8))) short short8;
typedef __attribute__((ext_vector_type(4))) float f32x4;
typedef __attribute__((ext_vector_type(16))) float f32x16;
typedef __attribute__((ext_vector_type(4))) unsigned short us4;

__device__ inline unsigned short f2bf(float f) {
  union { __hip_bfloat16 h; unsigned short u; } cv;
  cv.h = __float2bfloat16(f);
  return cv.u;
}

// ---------- prep: fragment-ordered weights (16x16 frags for proj) ----------
__global__ __launch_bounds__(256) void prep_w(
    const float* __restrict__ Wk, const float* __restrict__ Wq,
    const float* __restrict__ Wv, unsigned short* __restrict__ Wf) {
  const int idx = blockIdx.x * 256 + threadIdx.x;  // 12*32*64 = 24576
  const int lane = idx & 63, ks = (idx >> 6) & 31, t = idx >> 11;
  const int q = lane & 15, g = lane >> 4;
  const int m = t >> 2, h = (t & 3) * 16 + q;
  const float* W = (m == 0) ? Wk : (m == 1) ? Wq : Wv;
  const float sc = (m == 1) ? QSCALE : 1.f;
  const int e0 = ks * 32 + g * 8;
  unsigned short v[8];
  #pragma unroll
  for (int j = 0; j < 8; ++j) v[j] = f2bf(W[(e0 + j) * 64 + h] * sc);
  *(short8*)&Wf[(size_t)idx * 8] = *(short8*)v;
}

// ---------- QKV projection (x REPS for measurement) ------------------------
__global__ __launch_bounds__(256) void qkv_proj(
    const float* __restrict__ x,
    const float* __restrict__ bk, const float* __restrict__ bq,
    const float* __restrict__ bv, const unsigned short* __restrict__ Wf,
    unsigned short* __restrict__ kf, unsigned short* __restrict__ qf,
    unsigned short* __restrict__ vf) {
  __shared__ alignas(16) unsigned short xs[2][32][264];

  const int tid = threadIdx.x;
  const long row0 = (long)blockIdx.x * 32;
  const int w = tid >> 6, lane = tid & 63;
  const int q = lane & 15, g = lane >> 4;

  const float4* xg = (const float4*)&x[row0 * EE];  // 32 rows x 256 f4

  for (int rep = 0; rep < REPS; ++rep) {
    __syncthreads();  // xs reused as img at end of previous rep
    #pragma unroll
    for (int i = 0; i < 8; ++i) {
      const int flat = i * 256 + tid;
      const int rr = flat >> 6, c4 = flat & 63;
      const float4 xv = xg[rr * 256 + c4];
      us4 pk = {f2bf(xv.x), f2bf(xv.y), f2bf(xv.z), f2bf(xv.w)};
      *(us4*)&xs[0][rr][c4 * 4] = pk;
    }
    __syncthreads();

    const f32x4 z = {0.f, 0.f, 0.f, 0.f};
    f32x4 acc00 = z, acc01 = z, acc02 = z;
    f32x4 acc10 = z, acc11 = z, acc12 = z;
    const unsigned short* wf0 = &Wf[(size_t)(3 * w) * 16384 + (size_t)lane * 8];

    float4 st[8];
    #pragma unroll
    for (int cc = 0; cc < 4; ++cc) {
      if (cc < 3) {
        #pragma unroll
        for (int i = 0; i < 8; ++i) {
          const int flat = i * 256 + tid;
          const int rr = flat >> 6, c4 = flat & 63;
          st[i] = xg[rr * 256 + (cc + 1) * 64 + c4];
        }
      }
      #pragma unroll
      for (int ksl = 0; ksl < 8; ++ksl) {
        const short8 a0 = *(const short8*)&xs[cc & 1][q][ksl * 32 + g * 8];
        const short8 a1 = *(const short8*)&xs[cc & 1][16 + q][ksl * 32 + g * 8];
        const int ks = cc * 8 + ksl;
        const short8 b0 = *(const short8*)&wf0[ks * 512];
        const short8 b1 = *(const short8*)&wf0[16384 + ks * 512];
        const short8 b2 = *(const short8*)&wf0[32768 + ks * 512];
        acc00 = __builtin_amdgcn_mfma_f32_16x16x32_bf16(a0, b0, acc00, 0, 0, 0);
        acc10 = __builtin_amdgcn_mfma_f32_16x16x32_bf16(a1, b0, acc10, 0, 0, 0);
        acc01 = __builtin_amdgcn_mfma_f32_16x16x32_bf16(a0, b1, acc01, 0, 0, 0);
        acc11 = __builtin_amdgcn_mfma_f32_16x16x32_bf16(a1, b1, acc11, 0, 0, 0);
        acc02 = __builtin_amdgcn_mfma_f32_16x16x32_bf16(a0, b2, acc02, 0, 0, 0);
        acc12 = __builtin_amdgcn_mfma_f32_16x16x32_bf16(a1, b2, acc12, 0, 0, 0);
      }
      if (cc < 3) {
        #pragma unroll
        for (int i = 0; i < 8; ++i) {
          const int flat = i * 256 + tid;
          const int rr = flat >> 6, c4 = flat & 63;
          us4 pk = {f2bf(st[i].x), f2bf(st[i].y), f2bf(st[i].z), f2bf(st[i].w)};
          *(us4*)&xs[(cc + 1) & 1][rr][c4 * 4] = pk;
        }
      }
      __syncthreads();
    }

    // epilogue: pack D into LDS fragment images, then coalesced stores
    unsigned short* img = (unsigned short*)xs;
    #pragma unroll
    for (int i = 0; i < 3; ++i) {
      const int tgl = 3 * w + i;
      const int mm = tgl >> 2, hb = tgl & 3;
      const int h = hb * 16 + q;
      const float bias = (mm == 0) ? bk[h] : (mm == 1) ? bq[h] * QSCALE : bv[h];
      #pragma unroll
      for (int stp = 0; stp < 2; ++stp) {
        const f32x4 a = (stp == 0) ? ((i == 0) ? acc00 : (i == 1) ? acc01 : acc02)
                                   : ((i == 0) ? acc10 : (i == 1) ? acc11 : acc12);
        #pragma unroll
        for (int r = 0; r < 4; ++r) {
          const int tl5 = stp * 16 + 4 * g + r;
          const unsigned short ov = f2bf(a[r] + bias);
          if (mm == 2) {
            const int lane32v = ((hb & 1) * 16 + q) + 32 * ((tl5 >> 3) & 1);
            img[4096 + (hb >> 1) * 1024 + ((tl5 >> 4) & 1) * 512 +
                lane32v * 8 + (tl5 & 7)] = ov;
          } else {
            const int lane32 = tl5 + 32 * ((q >> 3) & 1);
            img[mm * 2048 + hb * 512 + lane32 * 8 + (q & 7)] = ov;
          }
        }
      }
    }
    __syncthreads();
    const size_t obase = (size_t)(row0 >> 11) * 131072 +
                         (size_t)((row0 & 2047) >> 5) * 2048;
    const int o = tid * 8;
    *(short8*)&kf[obase + o] = *(const short8*)&img[o];
    *(short8*)&qf[obase + o] = *(const short8*)&img[2048 + o];
    *(short8*)&vf[obase + o] = *(const short8*)&img[4096 + o];
  }
}

// ---------- flash attention (x REPS for measurement) -----------------------
#define BODY(KC, KN, tt, PREF) do {                                          \
    const unsigned short* vp_ = vfb + (size_t)(tt) * 2048;                   \
    const short8 V00 = *(const short8*)&vp_[0];                              \
    const short8 V10 = *(const short8*)&vp_[1024];                           \
    if (PREF) {                                                              \
      const unsigned short* kp_ = kfb + (size_t)((tt) + stride) * 2048;      \
      KN[0] = *(const short8*)&kp_[0];                                       \
      KN[1] = *(const short8*)&kp_[512];                                     \
      KN[2] = *(const short8*)&kp_[1024];                                    \
      KN[3] = *(const short8*)&kp_[1536];                                    \
    }                                                                        \
    f32x16 S;                                                                \
    _Pragma("unroll")                                                        \
    for (int r = 0; r < 16; ++r) S[r] = 0.f;                                 \
    __builtin_amdgcn_s_setprio(1);                                           \
    S = __builtin_amdgcn_mfma_f32_32x32x16_bf16(KC[0], Qf0, S, 0, 0, 0);     \
    S = __builtin_amdgcn_mfma_f32_32x32x16_bf16(KC[1], Qf1, S, 0, 0, 0);     \
    S = __builtin_amdgcn_mfma_f32_32x32x16_bf16(KC[2], Qf2, S, 0, 0, 0);     \
    S = __builtin_amdgcn_mfma_f32_32x32x16_bf16(KC[3], Qf3, S, 0, 0, 0);     \
    __builtin_amdgcn_s_setprio(0);                                           \
    const int k0_ = (tt) * 32;                                               \
    if (k0_ + 31 > q0) {                                                     \
      _Pragma("unroll")                                                      \
      for (int r = 0; r < 16; ++r) {                                         \
        const int key = (r & 3) + 8 * (r >> 2) + 4 * hf;                     \
        if (k0_ + key > qg) S[r] = -INFINITY;                                \
      }                                                                      \
    }                                                                        \
    float pmax = S[0];                                                       \
    _Pragma("unroll")                                                        \
    for (int r = 1; r < 16; ++r) pmax = fmaxf(pmax, S[r]);                   \
    if (!__all(pmax <= m + 8.0f)) {                                          \
      const float pm2 = fmaxf(pmax, __shfl_xor(pmax, 32));                   \
      const float nm = fmaxf(m, pm2);                                        \
      const float rs = __builtin_amdgcn_exp2f(m - nm);                       \
      l *= rs;                                                               \
      _Pragma("unroll")                                                      \
      for (int r = 0; r < 16; ++r) { O0[r] *= rs; O1[r] *= rs; }             \
      m = nm;                                                                \
    }                                                                        \
    float ps = 0.f;                                                          \
    _Pragma("unroll")                                                        \
    for (int r = 0; r < 16; ++r) {                                           \
      S[r] = __builtin_amdgcn_exp2f(S[r] - m); ps += S[r];                   \
    }                                                                        \
    l += ps;                                                                 \
    unsigned wa0, wa1, wa2, wa3, wb0, wb1, wb2, wb3;                         \
    asm("v_cvt_pk_bf16_f32 %0, %1, %2" : "=v"(wa0) : "v"(S[0]), "v"(S[1])); \
    asm("v_cvt_pk_bf16_f32 %0, %1, %2" : "=v"(wb0) : "v"(S[2]), "v"(S[3])); \
    asm("v_cvt_pk_bf16_f32 %0, %1, %2" : "=v"(wa1) : "v"(S[4]), "v"(S[5])); \
    asm("v_cvt_pk_bf16_f32 %0, %1, %2" : "=v"(wb1) : "v"(S[6]), "v"(S[7])); \
    asm("v_cvt_pk_bf16_f32 %0, %1, %2" : "=v"(wa2) : "v"(S[8]), "v"(S[9])); \
    asm("v_cvt_pk_bf16_f32 %0, %1, %2" : "=v"(wb2) : "v"(S[10]), "v"(S[11]));\
    asm("v_cvt_pk_bf16_f32 %0, %1, %2" : "=v"(wa3) : "v"(S[12]), "v"(S[13]));\
    asm("v_cvt_pk_bf16_f32 %0, %1, %2" : "=v"(wb3) : "v"(S[14]), "v"(S[15]));\
    { /* ks=0: dest fragment needs u = hf */                                 \
      const unsigned sA = hf ? wa1 : wa0, sB = hf ? wb1 : wb0;               \
      const unsigned tA = hf ? wa0 : wa1, tB = hf ? wb0 : wb1;               \
      const unsigned xA = __shfl_xor((int)tA, 32);                           \
      const unsigned xB = __shfl_xor((int)tB, 32);                           \
      union { unsigned u[4]; short8 s; } pf_;                                \
      pf_.u[0] = hf ? xA : sA; pf_.u[1] = hf ? xB : sB;                      \
      pf_.u[2] = hf ? sA : xA; pf_.u[3] = hf ? sB : xB;                      \
      __builtin_amdgcn_s_setprio(1);                                         \
      O0 = __builtin_amdgcn_mfma_f32_32x32x16_bf16(V00, pf_.s, O0, 0, 0, 0); \
      O1 = __builtin_amdgcn_mfma_f32_32x32x16_bf16(V10, pf_.s, O1, 0, 0, 0); \
      __builtin_amdgcn_s_setprio(0);                                         \
    }                                                                        \
    { /* ks=1: u = 2 + hf */                                                 \
      const short8 V01 = *(const short8*)&vp_[512];                          \
      const short8 V11 = *(const short8*)&vp_[1536];                         \
      const unsigned sA = hf ? wa3 : wa2, sB = hf ? wb3 : wb2;               \
      const unsigned tA = hf ? wa2 : wa3, tB = hf ? wb2 : wb3;               \
      const unsigned xA = __shfl_xor((int)tA, 32);                           \
      const unsigned xB = __shfl_xor((int)tB, 32);                           \
      union { unsigned u[4]; short8 s; } pf_;                                \
      pf_.u[0] = hf ? xA : sA; pf_.u[1] = hf ? xB : sB;                      \
      pf_.u[2] = hf ? sA : xA; pf_.u[3] = hf ? sB : xB;                      \
      __builtin_amdgcn_s_setprio(1);                                         \
      O0 = __builtin_amdgcn_mfma_f32_32x32x16_bf16(V01, pf_.s, O0, 0, 0, 0); \
      O1 = __builtin_amdgcn_mfma_f32_32x32x16_bf16(V11, pf_.s, O1, 0, 0, 0); \
      __builtin_amdgcn_s_setprio(0);                                         \
    }                                                                        \
  } while (0)

__global__ __launch_bounds__(1024, 4) void attn_fwd(
    const unsigned short* __restrict__ qf, const unsigned short* __restrict__ kf,
    const unsigned short* __restrict__ vf, float* __restrict__ out) {
  __shared__ float accS[16][32][65];
  __shared__ float mlS[16][2][32];

  const int tid = threadIdx.x;
  const int w = tid >> 6, lane = tid & 63;   // w: 0..15
  const int q = lane & 31, hf = lane >> 5;

  const int b = blockIdx.x & 7;
  const int p = blockIdx.x >> 3;          // pair 0..31 (strips of 32 rows)
  const int s1 = 63 - p;
  const int nt0 = p + 1, nt1 = 64 - p;    // 32-key tiles; nt0+nt1 = 65
  int k = (16 * nt0 + 32) / 65;
  if (k < 1) k = 1;
  if (k > 15) k = 15;

  const bool onS0 = (w < k);
  const int s = onS0 ? p : s1;
  const int nt = onS0 ? nt0 : nt1;
  const int stride = onS0 ? k : (16 - k);

  const int q0 = s * 32;
  const int qg = q0 + q;

  const unsigned short* kfb = kf + (size_t)b * 131072 + (size_t)lane * 8;
  const unsigned short* vfb = vf + (size_t)b * 131072 + (size_t)lane * 8;
  const unsigned short* qfb = qf + (size_t)b * 131072 + (size_t)s * 2048 +
                              (size_t)lane * 8;
  const short8 Qf0 = *(const short8*)&qfb[0];
  const short8 Qf1 = *(const short8*)&qfb[512];
  const short8 Qf2 = *(const short8*)&qfb[1024];
  const short8 Qf3 = *(const short8*)&qfb[1536];

  for (int rep = 0; rep < REPS; ++rep) {
    __syncthreads();  // accS/mlS reuse across reps

    float m = -3.0e38f, l = 0.f;
    f32x16 O0, O1;
    #pragma unroll
    for (int r = 0; r < 16; ++r) { O0[r] = 0.f; O1[r] = 0.f; }

    int t = onS0 ? w : (w - k);
    {
      short8 A[4], B[4];
      const unsigned short* kp0 = kfb + (size_t)t * 2048;
      A[0] = *(const short8*)&kp0[0];
      A[1] = *(const short8*)&kp0[512];
      A[2] = *(const short8*)&kp0[1024];
      A[3] = *(const short8*)&kp0[1536];
      for (;;) {
        bool pf = (t + stride) < nt;
        BODY(A, B, t, pf);
        if (!pf) break;
        t += stride;
        pf = (t + stride) < nt;
        BODY(B, A, t, pf);
        if (!pf) break;
        t += stride;
      }
    }

    const float lq = l + __shfl_xor(l, 32);
    #pragma unroll
    for (int r = 0; r < 16; ++r) {
      const int hh0 = (r & 3) + 8 * (r >> 2) + 4 * hf;
      accS[w][q][hh0] = O0[r];
      accS[w][q][hh0 + 32] = O1[r];
    }
    if (hf == 0) { mlS[w][0][q] = m; mlS[w][1][q] = lq; }
    __syncthreads();

    const int half_t = tid >> 9;
    const int sm = half_t ? s1 : p;
    const int lo = half_t ? k : 0, hi2 = half_t ? 16 : k;
    const int idx = tid & 511;
    const int hh = idx & 63;
    const int qb0 = idx >> 6;               // 0..7
    const long obase = ((long)b * TT + (long)sm * 32) * 64;
    #pragma unroll
    for (int kk = 0; kk < 4; ++kk) {
      const int qv = qb0 + 8 * kk;
      float M = -INFINITY;
      for (int i = lo; i < hi2; ++i) M = fmaxf(M, mlS[i][0][qv]);
      float L = 0.f, acc = 0.f;
      for (int i = lo; i < hi2; ++i) {
        const float fi = __builtin_amdgcn_exp2f(mlS[i][0][qv] - M);
        L += fi * mlS[i][1][qv];
        acc += fi * accS[i][qv][hh];
      }
      out[obase + (long)qv * 64 + hh] = acc / L;
    }
  }
}

extern "C" void kernel_launch(void* const* d_in, const int* in_sizes, int n_in,
                              void* d_out, int out_size, void* d_ws, size_t ws_size,
                              hipStream_t stream) {
  const float* x  = (const float*)d_in[0];
  const float* Wk = (const float*)d_in[1];
  const float* bk = (const float*)d_in[2];
  const float* Wq = (const float*)d_in[3];
  const float* bq = (const float*)d_in[4];
  const float* Wv = (const float*)d_in[5];
  const float* bv = (const float*)d_in[6];
  float* out = (float*)d_out;

  unsigned short* qfb = (unsigned short*)d_ws;             // [B][64 strips][2048]
  unsigned short* kfb = qfb + (size_t)1048576;             // [B][64 tiles][2048]
  unsigned short* vfb = kfb + (size_t)1048576;             // [B][64 tiles][2048]
  unsigned short* Wf  = vfb + (size_t)1048576;             // [12][32][64][8]

  prep_w<<<dim3(96), 256, 0, stream>>>(Wk, Wq, Wv, Wf);
  qkv_proj<<<dim3(512), 256, 0, stream>>>(x, bk, bq, bv, Wf, kfb, qfb, vfb);
  attn_fwd<<<dim3(256), 1024, 0, stream>>>(qfb, kfb, vfb, out);
}

// Round 14
// 70.346 us; speedup vs baseline: 1.8109x; 1.8109x over previous
//
#include <hip/hip_runtime.h>
#include <hip/hip_bf16.h>
#include <math.h>

#define BB 8
#define TT 2048
#define EE 1024
#define HH 64
// 1/sqrt(64) * log2(e): fold into q so scores are in exp2 domain
#define QSCALE 0.18033688011112042f

typedef __attribute__((ext_vector_type(8))) short short8;
typedef __attribute__((ext_vector_type(4))) float f32x4;
typedef __attribute__((ext_vector_type(16))) float f32x16;
typedef __attribute__((ext_vector_type(4))) unsigned short us4;

__device__ inline unsigned short f2bf(float f) {
  union { __hip_bfloat16 h; unsigned short u; } cv;
  cv.h = __float2bfloat16(f);
  return cv.u;
}

// ---------- prep: fragment-ordered weights (16x16 frags for proj) ----------
__global__ __launch_bounds__(256) void prep_w(
    const float* __restrict__ Wk, const float* __restrict__ Wq,
    const float* __restrict__ Wv, unsigned short* __restrict__ Wf) {
  const int idx = blockIdx.x * 256 + threadIdx.x;  // 12*32*64 = 24576
  const int lane = idx & 63, ks = (idx >> 6) & 31, t = idx >> 11;
  const int q = lane & 15, g = lane >> 4;
  const int m = t >> 2, h = (t & 3) * 16 + q;
  const float* W = (m == 0) ? Wk : (m == 1) ? Wq : Wv;
  const float sc = (m == 1) ? QSCALE : 1.f;
  const int e0 = ks * 32 + g * 8;
  unsigned short v[8];
  #pragma unroll
  for (int j = 0; j < 8; ++j) v[j] = f2bf(W[(e0 + j) * 64 + h] * sc);
  *(short8*)&Wf[(size_t)idx * 8] = *(short8*)v;
}

// ---------- QKV projection v3: barrier-free, direct x loads ----------------
// 16 rows/block, 1024 blocks, 4 waves. Wave w owns tiles {w, 4+w, 8+w}
// (h-block w of K, Q, V). A-frag loaded straight from x (float4 x2 + cvt_pk);
// no staging LDS, no K-loop barriers, minimal VGPR -> 4 waves/SIMD.
__global__ __launch_bounds__(256) void qkv_proj(
    const float* __restrict__ x,
    const float* __restrict__ bk, const float* __restrict__ bq,
    const float* __restrict__ bv, const unsigned short* __restrict__ Wf,
    unsigned short* __restrict__ kf, unsigned short* __restrict__ qf,
    unsigned short* __restrict__ vf) {
  __shared__ alignas(16) unsigned short img[3072];  // kf|qf|vf half-tile images

  const int tid = threadIdx.x;
  const long row0 = (long)blockIdx.x * 16;
  const int w = tid >> 6, lane = tid & 63;
  const int q = lane & 15, g = lane >> 4;

  const float* xr = x + (row0 + q) * EE + g * 8;   // lane's row, col group
  const unsigned short* wf0 = &Wf[(size_t)w * 16384 + (size_t)lane * 8];

  const f32x4 z = {0.f, 0.f, 0.f, 0.f};
  f32x4 acc0 = z, acc1 = z, acc2 = z;

  #pragma unroll 4
  for (int ks = 0; ks < 32; ++ks) {
    const float4 fa = *(const float4*)&xr[ks * 32];
    const float4 fb = *(const float4*)&xr[ks * 32 + 4];
    unsigned p0, p1, p2, p3;
    asm("v_cvt_pk_bf16_f32 %0, %1, %2" : "=v"(p0) : "v"(fa.x), "v"(fa.y));
    asm("v_cvt_pk_bf16_f32 %0, %1, %2" : "=v"(p1) : "v"(fa.z), "v"(fa.w));
    asm("v_cvt_pk_bf16_f32 %0, %1, %2" : "=v"(p2) : "v"(fb.x), "v"(fb.y));
    asm("v_cvt_pk_bf16_f32 %0, %1, %2" : "=v"(p3) : "v"(fb.z), "v"(fb.w));
    union { unsigned u[4]; short8 s; } af;
    af.u[0] = p0; af.u[1] = p1; af.u[2] = p2; af.u[3] = p3;
    const short8 b0 = *(const short8*)&wf0[ks * 512];
    const short8 b1 = *(const short8*)&wf0[65536 + ks * 512];
    const short8 b2 = *(const short8*)&wf0[131072 + ks * 512];
    acc0 = __builtin_amdgcn_mfma_f32_16x16x32_bf16(af.s, b0, acc0, 0, 0, 0);
    acc1 = __builtin_amdgcn_mfma_f32_16x16x32_bf16(af.s, b1, acc1, 0, 0, 0);
    acc2 = __builtin_amdgcn_mfma_f32_16x16x32_bf16(af.s, b2, acc2, 0, 0, 0);
  }

  // epilogue: D[row=4g+r][col=q], h = w*16+q. Pack into compact half-tile
  // images in LDS, then 256B-contiguous short8 stores.
  const int h = w * 16 + q;
  const float biask = bk[h], biasq = bq[h] * QSCALE, biasv = bv[h];
  const int tl0 = (int)(row0 & 31);     // 0 or 16: which half of the 32-tile
  #pragma unroll
  for (int i = 0; i < 3; ++i) {
    const f32x4 a = (i == 0) ? acc0 : (i == 1) ? acc1 : acc2;
    const float bias = (i == 0) ? biask : (i == 1) ? biasq : biasv;
    #pragma unroll
    for (int r = 0; r < 4; ++r) {
      const int tlh = 4 * g + r;        // row within the 16-row half
      const unsigned short ov = f2bf(a[r] + bias);
      if (i == 2) {  // vf: c = hv*512 + lane32v*8 + j
        const int lane32v = ((w & 1) * 16 + q) + 32 * ((tlh >> 3) & 1);
        img[2048 + (w >> 1) * 512 + lane32v * 8 + (tlh & 7)] = ov;
      } else {       // kf/qf: c = hb*256 + u*128 + tlh*8 + j
        const int u = (q >> 3) & 1;
        img[i * 1024 + w * 256 + u * 128 + tlh * 8 + (q & 7)] = ov;
      }
    }
  }
  __syncthreads();

  const size_t tb = (size_t)(row0 >> 11) * 131072 +
                    (size_t)((row0 & 2047) >> 5) * 2048;
  const int ks0v = tl0 >> 4;            // 0 or 1
  if (tid < 128) {
    const int hb = tid >> 5, u = (tid >> 4) & 1, l16 = tid & 15;
    *(short8*)&kf[tb + hb * 512 + (l16 + tl0 + 32 * u) * 8] =
        *(const short8*)&img[tid * 8];
    const int hv = tid >> 6, ll = tid & 63;
    *(short8*)&vf[tb + hv * 1024 + ks0v * 512 + ll * 8] =
        *(const short8*)&img[2048 + tid * 8];
  } else if (tid < 256) {
    const int t2 = tid - 128;
    const int hb = t2 >> 5, u = (t2 >> 4) & 1, l16 = t2 & 15;
    *(short8*)&qf[tb + hb * 512 + (l16 + tl0 + 32 * u) * 8] =
        *(const short8*)&img[1024 + t2 * 8];
  }
}

// ---------- flash attention: 32x32 MFMA, paired blocks, 16 waves/block -----
#define BODY(KC, KN, tt, PREF) do {                                          \
    const unsigned short* vp_ = vfb + (size_t)(tt) * 2048;                   \
    const short8 V00 = *(const short8*)&vp_[0];                              \
    const short8 V10 = *(const short8*)&vp_[1024];                           \
    if (PREF) {                                                              \
      const unsigned short* kp_ = kfb + (size_t)((tt) + stride) * 2048;      \
      KN[0] = *(const short8*)&kp_[0];                                       \
      KN[1] = *(const short8*)&kp_[512];                                     \
      KN[2] = *(const short8*)&kp_[1024];                                    \
      KN[3] = *(const short8*)&kp_[1536];                                    \
    }                                                                        \
    f32x16 S;                                                                \
    _Pragma("unroll")                                                        \
    for (int r = 0; r < 16; ++r) S[r] = 0.f;                                 \
    __builtin_amdgcn_s_setprio(1);                                           \
    S = __builtin_amdgcn_mfma_f32_32x32x16_bf16(KC[0], Qf0, S, 0, 0, 0);     \
    S = __builtin_amdgcn_mfma_f32_32x32x16_bf16(KC[1], Qf1, S, 0, 0, 0);     \
    S = __builtin_amdgcn_mfma_f32_32x32x16_bf16(KC[2], Qf2, S, 0, 0, 0);     \
    S = __builtin_amdgcn_mfma_f32_32x32x16_bf16(KC[3], Qf3, S, 0, 0, 0);     \
    __builtin_amdgcn_s_setprio(0);                                           \
    const int k0_ = (tt) * 32;                                               \
    if (k0_ + 31 > q0) {                                                     \
      _Pragma("unroll")                                                      \
      for (int r = 0; r < 16; ++r) {                                         \
        const int key = (r & 3) + 8 * (r >> 2) + 4 * hf;                     \
        if (k0_ + key > qg) S[r] = -INFINITY;                                \
      }                                                                      \
    }                                                                        \
    float pmax = S[0];                                                       \
    _Pragma("unroll")                                                        \
    for (int r = 1; r < 16; ++r) pmax = fmaxf(pmax, S[r]);                   \
    if (!__all(pmax <= m + 8.0f)) {                                          \
      const float pm2 = fmaxf(pmax, __shfl_xor(pmax, 32));                   \
      const float nm = fmaxf(m, pm2);                                        \
      const float rs = __builtin_amdgcn_exp2f(m - nm);                       \
      l *= rs;                                                               \
      _Pragma("unroll")                                                      \
      for (int r = 0; r < 16; ++r) { O0[r] *= rs; O1[r] *= rs; }             \
      m = nm;                                                                \
    }                                                                        \
    float ps = 0.f;                                                          \
    _Pragma("unroll")                                                        \
    for (int r = 0; r < 16; ++r) {                                           \
      S[r] = __builtin_amdgcn_exp2f(S[r] - m); ps += S[r];                   \
    }                                                                        \
    l += ps;                                                                 \
    unsigned wa0, wa1, wa2, wa3, wb0, wb1, wb2, wb3;                         \
    asm("v_cvt_pk_bf16_f32 %0, %1, %2" : "=v"(wa0) : "v"(S[0]), "v"(S[1])); \
    asm("v_cvt_pk_bf16_f32 %0, %1, %2" : "=v"(wb0) : "v"(S[2]), "v"(S[3])); \
    asm("v_cvt_pk_bf16_f32 %0, %1, %2" : "=v"(wa1) : "v"(S[4]), "v"(S[5])); \
    asm("v_cvt_pk_bf16_f32 %0, %1, %2" : "=v"(wb1) : "v"(S[6]), "v"(S[7])); \
    asm("v_cvt_pk_bf16_f32 %0, %1, %2" : "=v"(wa2) : "v"(S[8]), "v"(S[9])); \
    asm("v_cvt_pk_bf16_f32 %0, %1, %2" : "=v"(wb2) : "v"(S[10]), "v"(S[11]));\
    asm("v_cvt_pk_bf16_f32 %0, %1, %2" : "=v"(wa3) : "v"(S[12]), "v"(S[13]));\
    asm("v_cvt_pk_bf16_f32 %0, %1, %2" : "=v"(wb3) : "v"(S[14]), "v"(S[15]));\
    { /* ks=0: dest fragment needs u = hf */                                 \
      const unsigned sA = hf ? wa1 : wa0, sB = hf ? wb1 : wb0;               \
      const unsigned tA = hf ? wa0 : wa1, tB = hf ? wb0 : wb1;               \
      const unsigned xA = __shfl_xor((int)tA, 32);                           \
      const unsigned xB = __shfl_xor((int)tB, 32);                           \
      union { unsigned u[4]; short8 s; } pf_;                                \
      pf_.u[0] = hf ? xA : sA; pf_.u[1] = hf ? xB : sB;                      \
      pf_.u[2] = hf ? sA : xA; pf_.u[3] = hf ? sB : xB;                      \
      __builtin_amdgcn_s_setprio(1);                                         \
      O0 = __builtin_amdgcn_mfma_f32_32x32x16_bf16(V00, pf_.s, O0, 0, 0, 0); \
      O1 = __builtin_amdgcn_mfma_f32_32x32x16_bf16(V10, pf_.s, O1, 0, 0, 0); \
      __builtin_amdgcn_s_setprio(0);                                         \
    }                                                                        \
    { /* ks=1: u = 2 + hf */                                                 \
      const short8 V01 = *(const short8*)&vp_[512];                          \
      const short8 V11 = *(const short8*)&vp_[1536];                         \
      const unsigned sA = hf ? wa3 : wa2, sB = hf ? wb3 : wb2;               \
      const unsigned tA = hf ? wa2 : wa3, tB = hf ? wb2 : wb3;               \
      const unsigned xA = __shfl_xor((int)tA, 32);                           \
      const unsigned xB = __shfl_xor((int)tB, 32);                           \
      union { unsigned u[4]; short8 s; } pf_;                                \
      pf_.u[0] = hf ? xA : sA; pf_.u[1] = hf ? xB : sB;                      \
      pf_.u[2] = hf ? sA : xA; pf_.u[3] = hf ? sB : xB;                      \
      __builtin_amdgcn_s_setprio(1);                                         \
      O0 = __builtin_amdgcn_mfma_f32_32x32x16_bf16(V01, pf_.s, O0, 0, 0, 0); \
      O1 = __builtin_amdgcn_mfma_f32_32x32x16_bf16(V11, pf_.s, O1, 0, 0, 0); \
      __builtin_amdgcn_s_setprio(0);                                         \
    }                                                                        \
  } while (0)

__global__ __launch_bounds__(1024, 4) void attn_fwd(
    const unsigned short* __restrict__ qf, const unsigned short* __restrict__ kf,
    const unsigned short* __restrict__ vf, float* __restrict__ out) {
  __shared__ float accS[16][32][65];
  __shared__ float mlS[16][2][32];

  const int tid = threadIdx.x;
  const int w = tid >> 6, lane = tid & 63;   // w: 0..15
  const int q = lane & 31, hf = lane >> 5;

  const int b = blockIdx.x & 7;
  const int p = blockIdx.x >> 3;          // pair 0..31 (strips of 32 rows)
  const int s1 = 63 - p;
  const int nt0 = p + 1, nt1 = 64 - p;    // 32-key tiles; nt0+nt1 = 65
  int k = (16 * nt0 + 32) / 65;
  if (k < 1) k = 1;
  if (k > 15) k = 15;

  const bool onS0 = (w < k);
  const int s = onS0 ? p : s1;
  const int nt = onS0 ? nt0 : nt1;
  const int stride = onS0 ? k : (16 - k);
  int t = onS0 ? w : (w - k);

  const int q0 = s * 32;
  const int qg = q0 + q;

  const unsigned short* kfb = kf + (size_t)b * 131072 + (size_t)lane * 8;
  const unsigned short* vfb = vf + (size_t)b * 131072 + (size_t)lane * 8;
  const unsigned short* qfb = qf + (size_t)b * 131072 + (size_t)s * 2048 +
                              (size_t)lane * 8;
  const short8 Qf0 = *(const short8*)&qfb[0];
  const short8 Qf1 = *(const short8*)&qfb[512];
  const short8 Qf2 = *(const short8*)&qfb[1024];
  const short8 Qf3 = *(const short8*)&qfb[1536];

  float m = -3.0e38f, l = 0.f;
  f32x16 O0, O1;
  #pragma unroll
  for (int r = 0; r < 16; ++r) { O0[r] = 0.f; O1[r] = 0.f; }

  {
    short8 A[4], B[4];
    const unsigned short* kp0 = kfb + (size_t)t * 2048;
    A[0] = *(const short8*)&kp0[0];
    A[1] = *(const short8*)&kp0[512];
    A[2] = *(const short8*)&kp0[1024];
    A[3] = *(const short8*)&kp0[1536];
    for (;;) {
      bool pf = (t + stride) < nt;
      BODY(A, B, t, pf);
      if (!pf) break;
      t += stride;
      pf = (t + stride) < nt;
      BODY(B, A, t, pf);
      if (!pf) break;
      t += stride;
    }
  }

  // per-wave state: l merged across halves; m already column-wide
  const float lq = l + __shfl_xor(l, 32);
  #pragma unroll
  for (int r = 0; r < 16; ++r) {
    const int hh0 = (r & 3) + 8 * (r >> 2) + 4 * hf;
    accS[w][q][hh0] = O0[r];
    accS[w][q][hh0 + 32] = O1[r];
  }
  if (hf == 0) { mlS[w][0][q] = m; mlS[w][1][q] = lq; }
  __syncthreads();

  // merge: tid<512 -> strip p (waves 0..k-1), tid>=512 -> strip s1 (k..15)
  const int half_t = tid >> 9;
  const int sm = half_t ? s1 : p;
  const int lo = half_t ? k : 0, hi2 = half_t ? 16 : k;
  const int idx = tid & 511;
  const int hh = idx & 63;
  const int qb0 = idx >> 6;               // 0..7
  const long obase = ((long)b * TT + (long)sm * 32) * 64;
  #pragma unroll
  for (int kk = 0; kk < 4; ++kk) {
    const int qv = qb0 + 8 * kk;
    float M = -INFINITY;
    for (int i = lo; i < hi2; ++i) M = fmaxf(M, mlS[i][0][qv]);
    float L = 0.f, acc = 0.f;
    for (int i = lo; i < hi2; ++i) {
      const float fi = __builtin_amdgcn_exp2f(mlS[i][0][qv] - M);
      L += fi * mlS[i][1][qv];
      acc += fi * accS[i][qv][hh];
    }
    out[obase + (long)qv * 64 + hh] = acc / L;
  }
}

extern "C" void kernel_launch(void* const* d_in, const int* in_sizes, int n_in,
                              void* d_out, int out_size, void* d_ws, size_t ws_size,
                              hipStream_t stream) {
  const float* x  = (const float*)d_in[0];
  const float* Wk = (const float*)d_in[1];
  const float* bk = (const float*)d_in[2];
  const float* Wq = (const float*)d_in[3];
  const float* bq = (const float*)d_in[4];
  const float* Wv = (const float*)d_in[5];
  const float* bv = (const float*)d_in[6];
  float* out = (float*)d_out;

  unsigned short* qfb = (unsigned short*)d_ws;             // [B][64 strips][2048]
  unsigned short* kfb = qfb + (size_t)1048576;             // [B][64 tiles][2048]
  unsigned short* vfb = kfb + (size_t)1048576;             // [B][64 tiles][2048]
  unsigned short* Wf  = vfb + (size_t)1048576;             // [12][32][64][8]

  prep_w<<<dim3(96), 256, 0, stream>>>(Wk, Wq, Wv, Wf);
  qkv_proj<<<dim3(1024), 256, 0, stream>>>(x, bk, bq, bv, Wf, kfb, qfb, vfb);
  attn_fwd<<<dim3(256), 1024, 0, stream>>>(qfb, kfb, vfb, out);
}

// Round 15
// 53.761 us; speedup vs baseline: 2.3696x; 1.3085x over previous
//
#include <hip/hip_runtime.h>
#include <hip/hip_bf16.h>
#include <math.h>

#define BB 8
#define TT 2048
#define EE 1024
#define HH 64
// 1/sqrt(64) * log2(e): fold into q so scores are in exp2 domain
#define QSCALE 0.18033688011112042f

typedef __attribute__((ext_vector_type(8))) short short8;
typedef __attribute__((ext_vector_type(4))) float f32x4;
typedef __attribute__((ext_vector_type(16))) float f32x16;
typedef __attribute__((ext_vector_type(4))) unsigned short us4;

__device__ inline unsigned short f2bf(float f) {
  union { __hip_bfloat16 h; unsigned short u; } cv;
  cv.h = __float2bfloat16(f);
  return cv.u;
}

// ---------- prep: fragment-ordered weights (16x16 frags for proj) ----------
__global__ __launch_bounds__(256) void prep_w(
    const float* __restrict__ Wk, const float* __restrict__ Wq,
    const float* __restrict__ Wv, unsigned short* __restrict__ Wf) {
  const int idx = blockIdx.x * 256 + threadIdx.x;  // 12*32*64 = 24576
  const int lane = idx & 63, ks = (idx >> 6) & 31, t = idx >> 11;
  const int q = lane & 15, g = lane >> 4;
  const int m = t >> 2, h = (t & 3) * 16 + q;
  const float* W = (m == 0) ? Wk : (m == 1) ? Wq : Wv;
  const float sc = (m == 1) ? QSCALE : 1.f;
  const int e0 = ks * 32 + g * 8;
  unsigned short v[8];
  #pragma unroll
  for (int j = 0; j < 8; ++j) v[j] = f2bf(W[(e0 + j) * 64 + h] * sc);
  *(short8*)&Wf[(size_t)idx * 8] = *(short8*)v;
}

// ---------- QKV projection v6: stage-once LDS, barrier-free K-loop ---------
// 16 rows/block, 1024 blocks (4/CU), 4 waves. Wave w owns tiles {w,4+w,8+w}.
// Stage 16x1024 fp32 -> bf16 LDS once (coalesced); K-loop: 1 ds_read_b128 +
// 3 coalesced B loads + 3 MFMA per ks. Low VGPR -> 4 waves/SIMD.
__global__ __launch_bounds__(256) void qkv_proj(
    const float* __restrict__ x,
    const float* __restrict__ bk, const float* __restrict__ bq,
    const float* __restrict__ bv, const unsigned short* __restrict__ Wf,
    unsigned short* __restrict__ kf, unsigned short* __restrict__ qf,
    unsigned short* __restrict__ vf) {
  __shared__ alignas(16) unsigned short xs[16][1040];  // pad -> 2-way (free)
  __shared__ alignas(16) unsigned short img[3072];     // kf|qf|vf images

  const int tid = threadIdx.x;
  const long row0 = (long)blockIdx.x * 16;
  const int w = tid >> 6, lane = tid & 63;
  const int q = lane & 15, g = lane >> 4;

  // stage: 16 rows x 1024 cols fp32 -> bf16, flat coalesced float4
  const float4* xg = (const float4*)&x[row0 * EE];
  #pragma unroll
  for (int i = 0; i < 16; ++i) {
    const int flat = i * 256 + tid;           // 0..4095
    const int rr = flat >> 8, c4 = flat & 255;
    const float4 xv = xg[flat];
    us4 pk = {f2bf(xv.x), f2bf(xv.y), f2bf(xv.z), f2bf(xv.w)};
    *(us4*)&xs[rr][c4 * 4] = pk;
  }
  __syncthreads();

  const f32x4 z = {0.f, 0.f, 0.f, 0.f};
  f32x4 acc0 = z, acc1 = z, acc2 = z;
  const unsigned short* wf0 = &Wf[(size_t)w * 16384 + (size_t)lane * 8];

  #pragma unroll 8
  for (int ks = 0; ks < 32; ++ks) {
    const short8 af = *(const short8*)&xs[q][ks * 32 + g * 8];
    const short8 b0 = *(const short8*)&wf0[ks * 512];
    const short8 b1 = *(const short8*)&wf0[65536 + ks * 512];
    const short8 b2 = *(const short8*)&wf0[131072 + ks * 512];
    acc0 = __builtin_amdgcn_mfma_f32_16x16x32_bf16(af, b0, acc0, 0, 0, 0);
    acc1 = __builtin_amdgcn_mfma_f32_16x16x32_bf16(af, b1, acc1, 0, 0, 0);
    acc2 = __builtin_amdgcn_mfma_f32_16x16x32_bf16(af, b2, acc2, 0, 0, 0);
  }

  // epilogue: pack D into compact half-tile images, then coalesced stores
  const int h = w * 16 + q;
  const float biask = bk[h], biasq = bq[h] * QSCALE, biasv = bv[h];
  const int tl0 = (int)(row0 & 31);     // 0 or 16: half of the 32-row tile
  #pragma unroll
  for (int i = 0; i < 3; ++i) {
    const f32x4 a = (i == 0) ? acc0 : (i == 1) ? acc1 : acc2;
    const float bias = (i == 0) ? biask : (i == 1) ? biasq : biasv;
    #pragma unroll
    for (int r = 0; r < 4; ++r) {
      const int tlh = 4 * g + r;        // row within the 16-row half
      const unsigned short ov = f2bf(a[r] + bias);
      if (i == 2) {
        const int lane32v = ((w & 1) * 16 + q) + 32 * ((tlh >> 3) & 1);
        img[2048 + (w >> 1) * 512 + lane32v * 8 + (tlh & 7)] = ov;
      } else {
        const int u = (q >> 3) & 1;
        img[i * 1024 + w * 256 + u * 128 + tlh * 8 + (q & 7)] = ov;
      }
    }
  }
  __syncthreads();

  const size_t tb = (size_t)(row0 >> 11) * 131072 +
                    (size_t)((row0 & 2047) >> 5) * 2048;
  const int ks0v = tl0 >> 4;            // 0 or 1
  if (tid < 128) {
    const int hb = tid >> 5, u = (tid >> 4) & 1, l16 = tid & 15;
    *(short8*)&kf[tb + hb * 512 + (l16 + tl0 + 32 * u) * 8] =
        *(const short8*)&img[tid * 8];
    const int hv = tid >> 6, ll = tid & 63;
    *(short8*)&vf[tb + hv * 1024 + ks0v * 512 + ll * 8] =
        *(const short8*)&img[2048 + tid * 8];
  } else if (tid < 256) {
    const int t2 = tid - 128;
    const int hb = t2 >> 5, u = (t2 >> 4) & 1, l16 = t2 & 15;
    *(short8*)&qf[tb + hb * 512 + (l16 + tl0 + 32 * u) * 8] =
        *(const short8*)&img[1024 + t2 * 8];
  }
}

// ---------- flash attention: 32x32 MFMA, paired blocks, 16 waves/block -----
// No K-prefetch (K/V are L2-resident; TLP hides latency); fits 128 VGPR.
#define BODY(tt) do {                                                        \
    const unsigned short* kp_ = kfb + (size_t)(tt) * 2048;                   \
    const short8 K0 = *(const short8*)&kp_[0];                               \
    const short8 K1 = *(const short8*)&kp_[512];                             \
    const short8 K2 = *(const short8*)&kp_[1024];                            \
    const short8 K3 = *(const short8*)&kp_[1536];                            \
    const unsigned short* vp_ = vfb + (size_t)(tt) * 2048;                   \
    const short8 V00 = *(const short8*)&vp_[0];                              \
    const short8 V10 = *(const short8*)&vp_[1024];                           \
    f32x16 S;                                                                \
    _Pragma("unroll")                                                        \
    for (int r = 0; r < 16; ++r) S[r] = 0.f;                                 \
    __builtin_amdgcn_s_setprio(1);                                           \
    S = __builtin_amdgcn_mfma_f32_32x32x16_bf16(K0, Qf0, S, 0, 0, 0);        \
    S = __builtin_amdgcn_mfma_f32_32x32x16_bf16(K1, Qf1, S, 0, 0, 0);        \
    S = __builtin_amdgcn_mfma_f32_32x32x16_bf16(K2, Qf2, S, 0, 0, 0);        \
    S = __builtin_amdgcn_mfma_f32_32x32x16_bf16(K3, Qf3, S, 0, 0, 0);        \
    __builtin_amdgcn_s_setprio(0);                                           \
    const int k0_ = (tt) * 32;                                               \
    if (k0_ + 31 > q0) {                                                     \
      _Pragma("unroll")                                                      \
      for (int r = 0; r < 16; ++r) {                                         \
        const int key = (r & 3) + 8 * (r >> 2) + 4 * hf;                     \
        if (k0_ + key > qg) S[r] = -INFINITY;                                \
      }                                                                      \
    }                                                                        \
    float pmax = S[0];                                                       \
    _Pragma("unroll")                                                        \
    for (int r = 1; r < 16; ++r) pmax = fmaxf(pmax, S[r]);                   \
    if (!__all(pmax <= m + 8.0f)) {                                          \
      const float pm2 = fmaxf(pmax, __shfl_xor(pmax, 32));                   \
      const float nm = fmaxf(m, pm2);                                        \
      const float rs = __builtin_amdgcn_exp2f(m - nm);                       \
      l *= rs;                                                               \
      _Pragma("unroll")                                                      \
      for (int r = 0; r < 16; ++r) { O0[r] *= rs; O1[r] *= rs; }             \
      m = nm;                                                                \
    }                                                                        \
    float ps = 0.f;                                                          \
    _Pragma("unroll")                                                        \
    for (int r = 0; r < 16; ++r) {                                           \
      S[r] = __builtin_amdgcn_exp2f(S[r] - m); ps += S[r];                   \
    }                                                                        \
    l += ps;                                                                 \
    unsigned wa0, wa1, wa2, wa3, wb0, wb1, wb2, wb3;                         \
    asm("v_cvt_pk_bf16_f32 %0, %1, %2" : "=v"(wa0) : "v"(S[0]), "v"(S[1])); \
    asm("v_cvt_pk_bf16_f32 %0, %1, %2" : "=v"(wb0) : "v"(S[2]), "v"(S[3])); \
    asm("v_cvt_pk_bf16_f32 %0, %1, %2" : "=v"(wa1) : "v"(S[4]), "v"(S[5])); \
    asm("v_cvt_pk_bf16_f32 %0, %1, %2" : "=v"(wb1) : "v"(S[6]), "v"(S[7])); \
    asm("v_cvt_pk_bf16_f32 %0, %1, %2" : "=v"(wa2) : "v"(S[8]), "v"(S[9])); \
    asm("v_cvt_pk_bf16_f32 %0, %1, %2" : "=v"(wb2) : "v"(S[10]), "v"(S[11]));\
    asm("v_cvt_pk_bf16_f32 %0, %1, %2" : "=v"(wa3) : "v"(S[12]), "v"(S[13]));\
    asm("v_cvt_pk_bf16_f32 %0, %1, %2" : "=v"(wb3) : "v"(S[14]), "v"(S[15]));\
    { /* ks=0: dest fragment needs u = hf */                                 \
      const unsigned sA = hf ? wa1 : wa0, sB = hf ? wb1 : wb0;               \
      const unsigned tA = hf ? wa0 : wa1, tB = hf ? wb0 : wb1;               \
      const unsigned xA = __shfl_xor((int)tA, 32);                           \
      const unsigned xB = __shfl_xor((int)tB, 32);                           \
      union { unsigned u[4]; short8 s; } pf_;                                \
      pf_.u[0] = hf ? xA : sA; pf_.u[1] = hf ? xB : sB;                      \
      pf_.u[2] = hf ? sA : xA; pf_.u[3] = hf ? sB : xB;                      \
      __builtin_amdgcn_s_setprio(1);                                         \
      O0 = __builtin_amdgcn_mfma_f32_32x32x16_bf16(V00, pf_.s, O0, 0, 0, 0); \
      O1 = __builtin_amdgcn_mfma_f32_32x32x16_bf16(V10, pf_.s, O1, 0, 0, 0); \
      __builtin_amdgcn_s_setprio(0);                                         \
    }                                                                        \
    { /* ks=1: u = 2 + hf */                                                 \
      const short8 V01 = *(const short8*)&vp_[512];                          \
      const short8 V11 = *(const short8*)&vp_[1536];                         \
      const unsigned sA = hf ? wa3 : wa2, sB = hf ? wb3 : wb2;               \
      const unsigned tA = hf ? wa2 : wa3, tB = hf ? wb2 : wb3;               \
      const unsigned xA = __shfl_xor((int)tA, 32);                           \
      const unsigned xB = __shfl_xor((int)tB, 32);                           \
      union { unsigned u[4]; short8 s; } pf_;                                \
      pf_.u[0] = hf ? xA : sA; pf_.u[1] = hf ? xB : sB;                      \
      pf_.u[2] = hf ? sA : xA; pf_.u[3] = hf ? sB : xB;                      \
      __builtin_amdgcn_s_setprio(1);                                         \
      O0 = __builtin_amdgcn_mfma_f32_32x32x16_bf16(V01, pf_.s, O0, 0, 0, 0); \
      O1 = __builtin_amdgcn_mfma_f32_32x32x16_bf16(V11, pf_.s, O1, 0, 0, 0); \
      __builtin_amdgcn_s_setprio(0);                                         \
    }                                                                        \
  } while (0)

__global__ __launch_bounds__(1024) void attn_fwd(
    const unsigned short* __restrict__ qf, const unsigned short* __restrict__ kf,
    const unsigned short* __restrict__ vf, float* __restrict__ out) {
  __shared__ float accS[16][32][65];
  __shared__ float mlS[16][2][32];

  const int tid = threadIdx.x;
  const int w = tid >> 6, lane = tid & 63;   // w: 0..15
  const int q = lane & 31, hf = lane >> 5;

  const int b = blockIdx.x & 7;
  const int p = blockIdx.x >> 3;          // pair 0..31 (strips of 32 rows)
  const int s1 = 63 - p;
  const int nt0 = p + 1, nt1 = 64 - p;    // 32-key tiles; nt0+nt1 = 65
  int k = (16 * nt0 + 32) / 65;
  if (k < 1) k = 1;
  if (k > 15) k = 15;

  const bool onS0 = (w < k);
  const int s = onS0 ? p : s1;
  const int nt = onS0 ? nt0 : nt1;
  const int stride = onS0 ? k : (16 - k);
  const int t0 = onS0 ? w : (w - k);

  const int q0 = s * 32;
  const int qg = q0 + q;

  const unsigned short* kfb = kf + (size_t)b * 131072 + (size_t)lane * 8;
  const unsigned short* vfb = vf + (size_t)b * 131072 + (size_t)lane * 8;
  const unsigned short* qfb = qf + (size_t)b * 131072 + (size_t)s * 2048 +
                              (size_t)lane * 8;
  const short8 Qf0 = *(const short8*)&qfb[0];
  const short8 Qf1 = *(const short8*)&qfb[512];
  const short8 Qf2 = *(const short8*)&qfb[1024];
  const short8 Qf3 = *(const short8*)&qfb[1536];

  float m = -3.0e38f, l = 0.f;
  f32x16 O0, O1;
  #pragma unroll
  for (int r = 0; r < 16; ++r) { O0[r] = 0.f; O1[r] = 0.f; }

  for (int t = t0; t < nt; t += stride) BODY(t);

  // per-wave state: l merged across halves; m already column-wide
  const float lq = l + __shfl_xor(l, 32);
  #pragma unroll
  for (int r = 0; r < 16; ++r) {
    const int hh0 = (r & 3) + 8 * (r >> 2) + 4 * hf;
    accS[w][q][hh0] = O0[r];
    accS[w][q][hh0 + 32] = O1[r];
  }
  if (hf == 0) { mlS[w][0][q] = m; mlS[w][1][q] = lq; }
  __syncthreads();

  // merge: tid<512 -> strip p (waves 0..k-1), tid>=512 -> strip s1 (k..15)
  const int half_t = tid >> 9;
  const int sm = half_t ? s1 : p;
  const int lo = half_t ? k : 0, hi2 = half_t ? 16 : k;
  const int idx = tid & 511;
  const int hh = idx & 63;
  const int qb0 = idx >> 6;               // 0..7
  const long obase = ((long)b * TT + (long)sm * 32) * 64;
  #pragma unroll
  for (int kk = 0; kk < 4; ++kk) {
    const int qv = qb0 + 8 * kk;
    float M = -INFINITY;
    for (int i = lo; i < hi2; ++i) M = fmaxf(M, mlS[i][0][qv]);
    float L = 0.f, acc = 0.f;
    for (int i = lo; i < hi2; ++i) {
      const float fi = __builtin_amdgcn_exp2f(mlS[i][0][qv] - M);
      L += fi * mlS[i][1][qv];
      acc += fi * accS[i][qv][hh];
    }
    out[obase + (long)qv * 64 + hh] = acc / L;
  }
}

extern "C" void kernel_launch(void* const* d_in, const int* in_sizes, int n_in,
                              void* d_out, int out_size, void* d_ws, size_t ws_size,
                              hipStream_t stream) {
  const float* x  = (const float*)d_in[0];
  const float* Wk = (const float*)d_in[1];
  const float* bk = (const float*)d_in[2];
  const float* Wq = (const float*)d_in[3];
  const float* bq = (const float*)d_in[4];
  const float* Wv = (const float*)d_in[5];
  const float* bv = (const float*)d_in[6];
  float* out = (float*)d_out;

  unsigned short* qfb = (unsigned short*)d_ws;             // [B][64 strips][2048]
  unsigned short* kfb = qfb + (size_t)1048576;             // [B][64 tiles][2048]
  unsigned short* vfb = kfb + (size_t)1048576;             // [B][64 tiles][2048]
  unsigned short* Wf  = vfb + (size_t)1048576;             // [12][32][64][8]

  prep_w<<<dim3(96), 256, 0, stream>>>(Wk, Wq, Wv, Wf);
  qkv_proj<<<dim3(1024), 256, 0, stream>>>(x, bk, bq, bv, Wf, kfb, qfb, vfb);
  attn_fwd<<<dim3(256), 1024, 0, stream>>>(qfb, kfb, vfb, out);
}

// Round 16
// 49.704 us; speedup vs baseline: 2.5630x; 1.0816x over previous
//
#include <hip/hip_runtime.h>
#include <hip/hip_bf16.h>
#include <math.h>

#define BB 8
#define TT 2048
#define EE 1024
#define HH 64
// 1/sqrt(64) * log2(e): fold into q so scores are in exp2 domain
#define QSCALE 0.18033688011112042f

typedef __attribute__((ext_vector_type(8))) short short8;
typedef __attribute__((ext_vector_type(4))) float f32x4;
typedef __attribute__((ext_vector_type(4))) unsigned short us4;

__device__ inline unsigned short f2bf(float f) {
  union { __hip_bfloat16 h; unsigned short u; } cv;
  cv.h = __float2bfloat16(f);
  return cv.u;
}

// ---------- prep: fragment-ordered weights --------------------------------
__global__ __launch_bounds__(256) void prep_w(
    const float* __restrict__ Wk, const float* __restrict__ Wq,
    const float* __restrict__ Wv, unsigned short* __restrict__ Wf) {
  const int idx = blockIdx.x * 256 + threadIdx.x;  // 12*32*64 = 24576
  const int lane = idx & 63, ks = (idx >> 6) & 31, t = idx >> 11;
  const int q = lane & 15, g = lane >> 4;
  const int m = t >> 2, h = (t & 3) * 16 + q;
  const float* W = (m == 0) ? Wk : (m == 1) ? Wq : Wv;
  const float sc = (m == 1) ? QSCALE : 1.f;
  const int e0 = ks * 32 + g * 8;
  unsigned short v[8];
  #pragma unroll
  for (int j = 0; j < 8; ++j) v[j] = f2bf(W[(e0 + j) * 64 + h] * sc);
  *(short8*)&Wf[(size_t)idx * 8] = *(short8*)v;
}

// ---------- QKV projection v7: stage-once LDS, barrier-free K-loop,
// epilogue emits R8 fragment layouts (kf/qf [t16][1024], vf [t32][2048]) ----
__global__ __launch_bounds__(256) void qkv_proj(
    const float* __restrict__ x,
    const float* __restrict__ bk, const float* __restrict__ bq,
    const float* __restrict__ bv, const unsigned short* __restrict__ Wf,
    unsigned short* __restrict__ kf, unsigned short* __restrict__ qf,
    unsigned short* __restrict__ vf) {
  __shared__ alignas(16) unsigned short xs[16][1040];  // pad: benign aliasing
  __shared__ alignas(16) unsigned short img[3072];     // kf|qf|vf images

  const int tid = threadIdx.x;
  const long row0 = (long)blockIdx.x * 16;
  const int w = tid >> 6, lane = tid & 63;
  const int q = lane & 15, g = lane >> 4;

  // stage: 16 rows x 1024 cols fp32 -> bf16, flat coalesced float4
  const float4* xg = (const float4*)&x[row0 * EE];
  #pragma unroll
  for (int i = 0; i < 16; ++i) {
    const int flat = i * 256 + tid;           // 0..4095
    const int rr = flat >> 8, c4 = flat & 255;
    const float4 xv = xg[flat];
    us4 pk = {f2bf(xv.x), f2bf(xv.y), f2bf(xv.z), f2bf(xv.w)};
    *(us4*)&xs[rr][c4 * 4] = pk;
  }
  __syncthreads();

  const f32x4 z = {0.f, 0.f, 0.f, 0.f};
  f32x4 acc0 = z, acc1 = z, acc2 = z;
  const unsigned short* wf0 = &Wf[(size_t)w * 16384 + (size_t)lane * 8];

  #pragma unroll 8
  for (int ks = 0; ks < 32; ++ks) {
    const short8 af = *(const short8*)&xs[q][ks * 32 + g * 8];
    const short8 b0 = *(const short8*)&wf0[ks * 512];
    const short8 b1 = *(const short8*)&wf0[65536 + ks * 512];
    const short8 b2 = *(const short8*)&wf0[131072 + ks * 512];
    acc0 = __builtin_amdgcn_mfma_f32_16x16x32_bf16(af, b0, acc0, 0, 0, 0);
    acc1 = __builtin_amdgcn_mfma_f32_16x16x32_bf16(af, b1, acc1, 0, 0, 0);
    acc2 = __builtin_amdgcn_mfma_f32_16x16x32_bf16(af, b2, acc2, 0, 0, 0);
  }

  // epilogue: D[row=4g+r][col=q], h = w*16+q. Pack into R8-layout images:
  //  kq: off = (h>>5)*512 + ((h&31)>>3)*128 + (tl&15)*8 + (h&7)
  //  v : off = (h>>4)*256(img) + ((tl&15)>>3)*128 + (h&15)*8 + (tl&7)
  const int h = w * 16 + q;
  const float biask = bk[h], biasq = bq[h] * QSCALE, biasv = bv[h];
  #pragma unroll
  for (int i = 0; i < 3; ++i) {
    const f32x4 a = (i == 0) ? acc0 : (i == 1) ? acc1 : acc2;
    const float bias = (i == 0) ? biask : (i == 1) ? biasq : biasv;
    #pragma unroll
    for (int r = 0; r < 4; ++r) {
      const int tlh = 4 * g + r;        // row within the block's 16
      const unsigned short ov = f2bf(a[r] + bias);
      if (i == 2) {
        img[2048 + w * 256 + (tlh >> 3) * 128 + q * 8 + (tlh & 7)] = ov;
      } else {
        const int g2 = (w & 1) * 2 + (q >> 3);
        img[i * 1024 + (w >> 1) * 512 + g2 * 128 + tlh * 8 + (q & 7)] = ov;
      }
    }
  }
  __syncthreads();

  const long bidx = row0 >> 11;
  const int tlg = (int)(row0 & 2047);
  const size_t tb16 = (size_t)bidx * 131072 + (size_t)(tlg >> 4) * 1024;
  const size_t vb32 = (size_t)bidx * 131072 + (size_t)(tlg >> 5) * 2048;
  const int ks0v = (tlg >> 4) & 1;      // (row0&31)>>4
  if (tid < 128) {
    *(short8*)&kf[tb16 + (size_t)tid * 8] = *(const short8*)&img[tid * 8];
    const int wv = tid >> 5, uu = (tid >> 4) & 1, qv = tid & 15;
    *(short8*)&vf[vb32 + wv * 512 + (2 * ks0v + uu) * 128 + qv * 8] =
        *(const short8*)&img[2048 + tid * 8];
  } else if (tid < 256) {
    const int t2 = tid - 128;
    *(short8*)&qf[tb16 + (size_t)t2 * 8] = *(const short8*)&img[1024 + t2 * 8];
  }
}

// ---------- flash attention (R8 verbatim): paired strips, 16x16 MFMA -------
#define BODY(KC0, KC1, KC2, KC3, KN0, KN1, KN2, KN3, tt, PREF) do {          \
    const unsigned short* vp_ = vfb + (size_t)(tt) * 2048;                   \
    const short8 V0 = *(const short8*)&vp_[0];                               \
    const short8 V1 = *(const short8*)&vp_[512];                             \
    const short8 V2 = *(const short8*)&vp_[1024];                            \
    const short8 V3 = *(const short8*)&vp_[1536];                            \
    if (PREF) {                                                              \
      const unsigned short* kp_ = kfb + (size_t)((tt) + stride) * 2048;      \
      KN0 = *(const short8*)&kp_[0];                                         \
      KN1 = *(const short8*)&kp_[512];                                       \
      KN2 = *(const short8*)&kp_[1024];                                      \
      KN3 = *(const short8*)&kp_[1536];                                      \
    }                                                                        \
    f32x4 sa = __builtin_amdgcn_mfma_f32_16x16x32_bf16(KC0, Qf0, z, 0,0,0);  \
    sa = __builtin_amdgcn_mfma_f32_16x16x32_bf16(KC1, Qf1, sa, 0,0,0);       \
    f32x4 sb = __builtin_amdgcn_mfma_f32_16x16x32_bf16(KC2, Qf0, z, 0,0,0);  \
    sb = __builtin_amdgcn_mfma_f32_16x16x32_bf16(KC3, Qf1, sb, 0,0,0);       \
    const int k0_ = (tt) * 32;                                               \
    if (k0_ + 31 > q0) {                                                     \
      _Pragma("unroll")                                                      \
      for (int r = 0; r < 4; ++r) {                                          \
        if (k0_ + 4 * g + r > qg) sa[r] = -INFINITY;                         \
        if (k0_ + 16 + 4 * g + r > qg) sb[r] = -INFINITY;                    \
      }                                                                      \
    }                                                                        \
    float pmax = fmaxf(fmaxf(fmaxf(sa[0], sa[1]), fmaxf(sa[2], sa[3])),      \
                       fmaxf(fmaxf(sb[0], sb[1]), fmaxf(sb[2], sb[3])));     \
    if (!__all(pmax <= m + 8.0f)) {                                          \
      float tmax = pmax;                                                     \
      tmax = fmaxf(tmax, __shfl_xor(tmax, 16));                              \
      tmax = fmaxf(tmax, __shfl_xor(tmax, 32));                              \
      const float nm = fmaxf(m, tmax);                                       \
      const float rs = __builtin_amdgcn_exp2f(m - nm);                       \
      l *= rs; o0 *= rs; o1 *= rs; o2 *= rs; o3 *= rs;                       \
      m = nm;                                                                \
    }                                                                        \
    float ps = 0.f;                                                          \
    _Pragma("unroll")                                                        \
    for (int r = 0; r < 4; ++r) {                                            \
      sa[r] = __builtin_amdgcn_exp2f(sa[r] - m); ps += sa[r];                \
      sb[r] = __builtin_amdgcn_exp2f(sb[r] - m); ps += sb[r];                \
    }                                                                        \
    l += ps;                                                                 \
    unsigned pw0, pw1, pw2, pw3;                                             \
    asm("v_cvt_pk_bf16_f32 %0, %1, %2" : "=v"(pw0) : "v"(sa[0]), "v"(sa[1]));\
    asm("v_cvt_pk_bf16_f32 %0, %1, %2" : "=v"(pw1) : "v"(sa[2]), "v"(sa[3]));\
    asm("v_cvt_pk_bf16_f32 %0, %1, %2" : "=v"(pw2) : "v"(sb[0]), "v"(sb[1]));\
    asm("v_cvt_pk_bf16_f32 %0, %1, %2" : "=v"(pw3) : "v"(sb[2]), "v"(sb[3]));\
    const int srcA = q + ((g & 1) << 5);                                     \
    const int srcB = srcA + 16;                                              \
    const unsigned r0a = __shfl((int)pw0, srcA);                             \
    const unsigned r1a = __shfl((int)pw1, srcA);                             \
    const unsigned r2a = __shfl((int)pw2, srcA);                             \
    const unsigned r3a = __shfl((int)pw3, srcA);                             \
    const unsigned r0b = __shfl((int)pw0, srcB);                             \
    const unsigned r1b = __shfl((int)pw1, srcB);                             \
    const unsigned r2b = __shfl((int)pw2, srcB);                             \
    const unsigned r3b = __shfl((int)pw3, srcB);                             \
    union { unsigned u[4]; short8 s; } pf_;                                  \
    const bool hi_ = (g >= 2);                                               \
    pf_.u[0] = hi_ ? r2a : r0a;                                              \
    pf_.u[1] = hi_ ? r3a : r1a;                                              \
    pf_.u[2] = hi_ ? r2b : r0b;                                              \
    pf_.u[3] = hi_ ? r3b : r1b;                                              \
    const short8 Pf = pf_.s;                                                 \
    o0 = __builtin_amdgcn_mfma_f32_16x16x32_bf16(V0, Pf, o0, 0,0,0);         \
    o1 = __builtin_amdgcn_mfma_f32_16x16x32_bf16(V1, Pf, o1, 0,0,0);         \
    o2 = __builtin_amdgcn_mfma_f32_16x16x32_bf16(V2, Pf, o2, 0,0,0);         \
    o3 = __builtin_amdgcn_mfma_f32_16x16x32_bf16(V3, Pf, o3, 0,0,0);         \
  } while (0)

__global__ __launch_bounds__(512) void attn_fwd(
    const unsigned short* __restrict__ qf, const unsigned short* __restrict__ kf,
    const unsigned short* __restrict__ vf, float* __restrict__ out) {
  __shared__ float accS[8][64][17];
  __shared__ float mlS[8][2][16];

  const int tid = threadIdx.x;
  const int w = tid >> 6, lane = tid & 63;
  const int q = lane & 15, g = lane >> 4;

  const int b = blockIdx.x & 7;
  const int p = blockIdx.x >> 3;           // pair 0..63
  const int s1 = 127 - p;
  const int nt0 = (p + 2) >> 1, nt1 = (129 - p) >> 1;   // nt0 + nt1 = 65
  int k = (8 * nt0 + 32) / 65;
  if (k < 1) k = 1;
  if (k > 7) k = 7;

  const bool onS0 = (w < k);
  const int s = onS0 ? p : s1;
  const int nt = onS0 ? nt0 : nt1;
  const int stride = onS0 ? k : (8 - k);
  int t = onS0 ? w : (w - k);

  const int q0 = s * 16;
  const int qg = q0 + q;

  const unsigned short* kfb = kf + (size_t)b * 131072 + (size_t)lane * 8;
  const unsigned short* vfb = vf + (size_t)b * 131072 + (size_t)lane * 8;
  const unsigned short* qfb = qf + (size_t)b * 131072 + (size_t)s * 1024 +
                              (size_t)lane * 8;
  const short8 Qf0 = *(const short8*)&qfb[0];
  const short8 Qf1 = *(const short8*)&qfb[512];

  const f32x4 z = {0.f, 0.f, 0.f, 0.f};
  float m = -3.0e38f, l = 0.f;
  f32x4 o0 = z, o1 = z, o2 = z, o3 = z;

  {
    short8 A0, A1, A2, A3, B0, B1, B2, B3;
    const unsigned short* kp0 = kfb + (size_t)t * 2048;
    A0 = *(const short8*)&kp0[0];
    A1 = *(const short8*)&kp0[512];
    A2 = *(const short8*)&kp0[1024];
    A3 = *(const short8*)&kp0[1536];
    for (;;) {
      bool pf = (t + stride) < nt;
      BODY(A0, A1, A2, A3, B0, B1, B2, B3, t, pf);
      if (!pf) break;
      t += stride;
      pf = (t + stride) < nt;
      BODY(B0, B1, B2, B3, A0, A1, A2, A3, t, pf);
      if (!pf) break;
      t += stride;
    }
  }

  // finalize per-wave state: l summed across g (2 shfl, once per kernel)
  float lq = l;
  lq += __shfl_xor(lq, 16);
  lq += __shfl_xor(lq, 32);
  #pragma unroll
  for (int hb = 0; hb < 4; ++hb) {
    const f32x4 a = (hb == 0) ? o0 : (hb == 1) ? o1 : (hb == 2) ? o2 : o3;
    #pragma unroll
    for (int r = 0; r < 4; ++r) accS[w][16 * hb + 4 * g + r][q] = a[r];
  }
  if (g == 0) { mlS[w][0][q] = m; mlS[w][1][q] = lq; }
  __syncthreads();

  // merge: tid<256 -> strip p (slots 0..k-1), tid>=256 -> strip 127-p (k..7)
  const int half = tid >> 8;
  const int sm = half ? s1 : p;
  const int lo = half ? k : 0, hi = half ? 8 : k;
  const int row = tid & 63, qq = (tid >> 6) & 3;
  const long obase = ((long)b * TT + sm * 16) * 64;
  #pragma unroll
  for (int kk = 0; kk < 4; ++kk) {
    const int qv = qq + 4 * kk;
    float M = -INFINITY;
    for (int i = lo; i < hi; ++i) M = fmaxf(M, mlS[i][0][qv]);
    float L = 0.f, acc = 0.f;
    for (int i = lo; i < hi; ++i) {
      const float fi = __builtin_amdgcn_exp2f(mlS[i][0][qv] - M);
      L += fi * mlS[i][1][qv];
      acc += fi * accS[i][row][qv];
    }
    out[obase + (long)qv * 64 + row] = acc / L;
  }
}

extern "C" void kernel_launch(void* const* d_in, const int* in_sizes, int n_in,
                              void* d_out, int out_size, void* d_ws, size_t ws_size,
                              hipStream_t stream) {
  const float* x  = (const float*)d_in[0];
  const float* Wk = (const float*)d_in[1];
  const float* bk = (const float*)d_in[2];
  const float* Wq = (const float*)d_in[3];
  const float* bq = (const float*)d_in[4];
  const float* Wv = (const float*)d_in[5];
  const float* bv = (const float*)d_in[6];
  float* out = (float*)d_out;

  unsigned short* qfb = (unsigned short*)d_ws;             // [B][128][1024]
  unsigned short* kfb = qfb + (size_t)1048576;             // [B][128][1024]
  unsigned short* vfb = kfb + (size_t)1048576;             // [B][64][2048]
  unsigned short* Wf  = vfb + (size_t)1048576;             // [12][32][64][8]

  prep_w<<<dim3(96), 256, 0, stream>>>(Wk, Wq, Wv, Wf);
  qkv_proj<<<dim3(1024), 256, 0, stream>>>(x, bk, bq, bv, Wf, kfb, qfb, vfb);
  attn_fwd<<<dim3(512), 512, 0, stream>>>(qfb, kfb, vfb, out);
}